// Round 1
// 207.432 us; speedup vs baseline: 1.0552x; 1.0552x over previous
//
#include <hip/hip_runtime.h>
#include <stdint.h>

// ---------------------------------------------------------------------------
// MADE flow layer, f32 I/O.
//   h  = relu(zp @ (W1*M1) + b1)     GEMM1: M=4096 N=4096 K=1024 (int8)
//   res= h @ (W2*M2) + b2            GEMM2: M=4096 N=2048 K=4096 (MX-fp8)
//   x[:, perm[i]] = zp*exp(log_s)+mu ; log_det exact via fused h.wsum2
//
// R16 change (vs R15 PASS @218.9us): fuse finale into gemm2.
// gemm2 was at its 2-barrier-structure ceiling (~32% of MX peak, matches
// m97-structure plateau); the visible waste was the res round-trip:
// gemm2 wrote res f32 (32MB), finale re-read it (+z 16MB) and wrote out
// (16MB). New gemm2f_k tiles 64 rows x 256 cols where the 256 cols are the
// PAIR {[n0,n0+128), [D+n0,D+n0+128)} so each thread holds matching mu and
// log_s for the same column -> epilogue computes x = z*exp(ls)+mu directly
// (identical math to the old f32 finale path). nb==0 blocks also emit
// log_det = ld[b] + sum(b2[D:]). res workspace + finale kernel deleted.
// Inner loop / staging / swizzle identical to the validated MX structure.
// ---------------------------------------------------------------------------

typedef float   f32x4  __attribute__((ext_vector_type(4)));
typedef int     i32x4  __attribute__((ext_vector_type(4)));
typedef int     i32x8  __attribute__((ext_vector_type(8)));

__device__ __forceinline__ uint8_t f2fp8(float f) {
    int p = __builtin_amdgcn_cvt_pk_fp8_f32(f, 0.0f, 0, false);
    return (uint8_t)(p & 0xff);
}
__device__ __forceinline__ int8_t f2i8(float v, float s) {
    float q = rintf(v * s);
    q = fminf(fmaxf(q, -127.0f), 127.0f);
    return (int8_t)q;
}

#define GLD16(g, l)                                                          \
    __builtin_amdgcn_global_load_lds(                                        \
        (const __attribute__((address_space(1))) uint32_t*)(g),              \
        (__attribute__((address_space(3))) uint32_t*)(l), 16, 0, 0)

#define MFMA_MX(a, b, c)                                                     \
    __builtin_amdgcn_mfma_scale_f32_16x16x128_f8f6f4(                        \
        (a), (b), (c), 0, 0, 0, 0x7F7F7F7F, 0, 0x7F7F7F7F)

// ---------------------------------------------------------------------------
// W1 masked transpose -> int8 x1024:
//   W1mT[j][i] = (j%(Dv-1) >= i) ? i8(1024*W1[i][j]) : 0
// Vectorized 8B write-back; first blocks also zero ld[0..B) + ws2[0..C).
// ---------------------------------------------------------------------------
__global__ __launch_bounds__(256) void mt1_k(
    const float* __restrict__ W, int8_t* __restrict__ WT, int R, int C, int Dv,
    float* __restrict__ ld, float* __restrict__ ws2, int B) {
    __shared__ int8_t t[64][68];
    const int c0 = blockIdx.x * 64, r0 = blockIdx.y * 64;
    const int tid = threadIdx.x;
    const int tx = tid & 63, ty = tid >> 6;

    const int fid = (blockIdx.y * gridDim.x + blockIdx.x) * 256 + tid;
    if (fid < B) ld[fid] = 0.0f;
    else if (fid < B + C) ws2[fid - B] = 0.0f;

    for (int rr = ty; rr < 64; rr += 4) {
        const int r = r0 + rr, c = c0 + tx;
        float v = W[(size_t)r * C + c];
        t[rr][tx] = ((c % (Dv - 1)) >= r) ? f2i8(v, 1024.0f) : (int8_t)0;
    }
    __syncthreads();
#pragma unroll
    for (int pass = 0; pass < 2; pass++) {
        const int cc = pass * 32 + (tid >> 3);
        const int j0 = (tid & 7) * 8;
        union { int8_t b[8]; uint64_t q; } v;
#pragma unroll
        for (int j = 0; j < 8; j++) v.b[j] = t[j0 + j][cc];
        *(uint64_t*)&WT[(size_t)(c0 + cc) * R + r0 + j0] = v.q;
    }
}

// ---------------------------------------------------------------------------
// W2 masked transpose -> fp8 x256 + fused masked row-sum of second half
// ---------------------------------------------------------------------------
__global__ __launch_bounds__(256) void mt2_k(
    const float* __restrict__ W, uint8_t* __restrict__ WT,
    float* __restrict__ ws2, int R, int C, int Dv) {
    __shared__ uint8_t t[64][68];
    const int c0 = blockIdx.x * 64, r0 = blockIdx.y * 64;
    const int tid = threadIdx.x;
    const int tx = tid & 63, ty = tid >> 6;
    const bool second = (c0 >= Dv);
    for (int rr = ty; rr < 64; rr += 4) {
        const int r = r0 + rr, c = c0 + tx;
        float v = W[(size_t)r * C + c];
        bool keep = ((c % Dv) > (r % (Dv - 1)));
        t[rr][tx] = keep ? f2fp8(v * 256.0f) : (uint8_t)0;
        if (second) {
            float s = keep ? v : 0.0f;
#pragma unroll
            for (int o = 32; o > 0; o >>= 1) s += __shfl_down(s, o, 64);
            if (tx == 0) atomicAdd(&ws2[r], s);
        }
    }
    __syncthreads();
#pragma unroll
    for (int pass = 0; pass < 2; pass++) {
        const int cc = pass * 32 + (tid >> 3);
        const int j0 = (tid & 7) * 8;
        union { uint8_t b[8]; uint64_t q; } v;
#pragma unroll
        for (int j = 0; j < 8; j++) v.b[j] = t[j0 + j][cc];
        *(uint64_t*)&WT[(size_t)(c0 + cc) * R + r0 + j0] = v.q;
    }
}

// zp[b][i] = i8(32 * z[b][perm[i]])
__global__ __launch_bounds__(256) void perm_k(
    const float* __restrict__ z, const int* __restrict__ perm,
    int8_t* __restrict__ zp, int D) {
    const int b = blockIdx.y;
    const int i = blockIdx.x * 256 + threadIdx.x;
    zp[(size_t)b * D + i] = f2i8(z[(size_t)b * D + perm[i]], 32.0f);
}

// ---------------------------------------------------------------------------
// GEMM1 (int8, K=64/MFMA, BK=128, 32KB LDS):
//   h = fp8(relu(acc/32768 + b1)) + fused exact partial log-det (f32 h).
// (unchanged from R15 — validated)
// ---------------------------------------------------------------------------
__global__ __launch_bounds__(256) void gemm1_k(
    const int8_t* __restrict__ A, const int8_t* __restrict__ Bt,
    const float* __restrict__ bias, const float* __restrict__ wsum2,
    uint8_t* __restrict__ Cout, float* __restrict__ ld,
    int M, int N, int K) {
    __shared__ __align__(16) int8_t Alds[128 * 128];
    __shared__ __align__(16) int8_t Blds[128 * 128];
    __shared__ float pdl[128];

    const int id   = blockIdx.x;
    const int xcd  = id & 7, s = id >> 3;     // s in [0,128)
    const int mb   = s & 31;
    const int nb   = xcd * 4 + (s >> 5);
    const int m0   = mb * 128;
    const int n0   = nb * 128;

    const int tid  = threadIdx.x;
    const int lane = tid & 63;
    const int w    = tid >> 6;
    const int wm   = (w & 1) * 64;
    const int wn   = (w >> 1) * 64;
    const int quad = lane >> 4;
    const int l16  = lane & 15;

    i32x4 acc[4][4];
#pragma unroll
    for (int i = 0; i < 4; i++)
#pragma unroll
        for (int j = 0; j < 4; j++) acc[i][j] = (i32x4)0;

    const int8_t* Ag[4];
    const int8_t* Bg[4];
    int8_t *Al[4], *Bl[4];
#pragma unroll
    for (int k = 0; k < 4; k++) {
        const int c  = tid + k * 256;
        const int so = ((c & 7) ^ ((c >> 3) & 7)) * 16;  // bytes
        Ag[k] = A + (size_t)(m0 + (c >> 3)) * K + so;
        Bg[k] = Bt + (size_t)(n0 + (c >> 3)) * K + so;
        Al[k] = &Alds[c * 16];
        Bl[k] = &Blds[c * 16];
    }

    const int sw   = l16 & 7;
    const int arow = (wm + l16) * 128;
    const int brow = (wn + l16) * 128;

    for (int kt = 0; kt < K; kt += 128) {
        __syncthreads();
#pragma unroll
        for (int k = 0; k < 4; k++) {
            GLD16(Ag[k] + kt, Al[k]);
            GLD16(Bg[k] + kt, Bl[k]);
        }
        __syncthreads();

#pragma unroll
        for (int kh = 0; kh < 2; kh++) {
            const int pc = ((kh * 4 + quad) ^ sw) * 16;
            i32x4 af[4], bfr[4];
#pragma unroll
            for (int mi = 0; mi < 4; mi++)
                af[mi] = *(const i32x4*)&Alds[arow + mi * 16 * 128 + pc];
#pragma unroll
            for (int ni = 0; ni < 4; ni++)
                bfr[ni] = *(const i32x4*)&Blds[brow + ni * 16 * 128 + pc];
#pragma unroll
            for (int mi = 0; mi < 4; mi++)
#pragma unroll
                for (int ni = 0; ni < 4; ni++)
                    acc[mi][ni] = __builtin_amdgcn_mfma_i32_16x16x64_i8(
                        af[mi], bfr[ni], acc[mi][ni], 0, 0, 0);
        }
    }

    // epilogue: C/D layout col = lane&15, row = quad*4 + reg;  h = acc/32768+b
    const float inv = 1.0f / 32768.0f;
    float bv[4], wv[4];
#pragma unroll
    for (int ni = 0; ni < 4; ni++) {
        bv[ni] = bias[n0 + wn + ni * 16 + l16];
        wv[ni] = wsum2[n0 + wn + ni * 16 + l16];
    }
    float pd[4][4];
#pragma unroll
    for (int mi = 0; mi < 4; mi++)
#pragma unroll
        for (int r = 0; r < 4; r++) pd[mi][r] = 0.0f;

#pragma unroll
    for (int mi = 0; mi < 4; mi++) {
        const int row = m0 + wm + mi * 16 + quad * 4;
#pragma unroll
        for (int ni = 0; ni < 4; ni++) {
            const int col = n0 + wn + ni * 16 + l16;
#pragma unroll
            for (int r = 0; r < 4; r++) {
                float v = fmaxf((float)acc[mi][ni][r] * inv + bv[ni], 0.0f);
                pd[mi][r] += v * wv[ni];
                Cout[(size_t)(row + r) * N + col] = f2fp8(v);
            }
        }
    }

#pragma unroll
    for (int off = 1; off < 16; off <<= 1)
#pragma unroll
        for (int mi = 0; mi < 4; mi++)
#pragma unroll
            for (int r = 0; r < 4; r++)
                pd[mi][r] += __shfl_xor(pd[mi][r], off, 16);

    __syncthreads();
    if ((w >> 1) == 0 && l16 == 0)
#pragma unroll
        for (int mi = 0; mi < 4; mi++)
#pragma unroll
            for (int r = 0; r < 4; r++)
                pdl[wm + mi * 16 + quad * 4 + r] = pd[mi][r];
    __syncthreads();
    if ((w >> 1) == 1 && l16 == 0)
#pragma unroll
        for (int mi = 0; mi < 4; mi++)
#pragma unroll
            for (int r = 0; r < 4; r++)
                pdl[wm + mi * 16 + quad * 4 + r] += pd[mi][r];
    __syncthreads();
    if (tid < 128) atomicAdd(&ld[m0 + tid], pdl[tid]);
}

// ---------------------------------------------------------------------------
// GEMM2 fused (MX fp8, K=128/MFMA, BK=128, 40KB LDS):
//   block = 64 rows x 256 cols, cols = PAIR {[n0,n0+128), [D+n0,D+n0+128)}
//   so each thread holds matching mu (acc ni<4) and log_s (acc ni>=4) for
//   the same column -> epilogue computes x = z*exp(ls)+mu directly.
//   nb==0 blocks also write log_det = ld[b] + sum(b2[D:]).
//   Staging/swizzle identical to the validated MX structure.
//   Grid: (D/128) * (B/64) = 512 blocks; nb = id&7 pins each n-pair to one
//   XCD (B slice = 1MB, L2-resident, reused by 64 blocks).
// ---------------------------------------------------------------------------
__global__ __launch_bounds__(256) void gemm2f_k(
    const uint8_t* __restrict__ A, const uint8_t* __restrict__ Bt,
    const float* __restrict__ b2, const int* __restrict__ perm,
    const float* __restrict__ z, const float* __restrict__ ld,
    float* __restrict__ out, int B, int D, int K) {
    __shared__ __align__(16) uint8_t Alds[64 * 128];
    __shared__ __align__(16) uint8_t Blds[256 * 128];
    __shared__ float red[4];

    const int id   = blockIdx.x;
    const int nb   = id & 7;          // n-pair block (8 total)
    const int s    = id >> 3;         // m-block (64 total)
    const int m0   = s * 64;
    const int n0   = nb * 128;

    const int tid  = threadIdx.x;
    const int lane = tid & 63;
    const int w    = tid >> 6;
    const int wm   = (w & 1) * 32;
    const int wn   = (w >> 1) * 64;
    const int quad = lane >> 4;
    const int l16  = lane & 15;

    f32x4 acc[2][8];
#pragma unroll
    for (int i = 0; i < 2; i++)
#pragma unroll
        for (int j = 0; j < 8; j++) acc[i][j] = (f32x4)0.0f;

    // staging: A = 64 rows x 128B (2 chunks/thread), B = 256 rows x 128B
    // (8 chunks/thread); rows 0..127 of B-tile = mu cols, 128..255 = ls cols
    const uint8_t* Ag[2];
    uint8_t* Al[2];
#pragma unroll
    for (int k = 0; k < 2; k++) {
        const int c  = tid + k * 256;
        const int so = ((c & 7) ^ ((c >> 3) & 7)) * 16;  // bytes
        Ag[k] = A + (size_t)(m0 + (c >> 3)) * K + so;
        Al[k] = &Alds[c * 16];
    }
    const uint8_t* Bg[8];
    uint8_t* Bl[8];
#pragma unroll
    for (int k = 0; k < 8; k++) {
        const int c  = tid + k * 256;
        const int r  = c >> 3;
        const int g  = (r < 128) ? (n0 + r) : (D + n0 + (r - 128));
        const int so = ((c & 7) ^ (r & 7)) * 16;  // bytes
        Bg[k] = Bt + (size_t)g * K + so;
        Bl[k] = &Blds[c * 16];
    }

    const int sw   = l16 & 7;
    const int pc0  = ((quad * 2) ^ sw) * 16;
    const int pc1  = ((quad * 2 + 1) ^ sw) * 16;
    const int arow = (wm + l16) * 128;
    int brow[8];
#pragma unroll
    for (int ni = 0; ni < 8; ni++)
        brow[ni] = ((ni >> 2) * 128 + wn + (ni & 3) * 16 + l16) * 128;

    for (int kt = 0; kt < K; kt += 128) {
        __syncthreads();
#pragma unroll
        for (int k = 0; k < 2; k++) GLD16(Ag[k] + kt, Al[k]);
#pragma unroll
        for (int k = 0; k < 8; k++) GLD16(Bg[k] + kt, Bl[k]);
        __syncthreads();

        union AB { int4 h2[2]; i32x8 v; };
        i32x8 af[2], bfr[8];
#pragma unroll
        for (int mi = 0; mi < 2; mi++) {
            AB t;
            t.h2[0] = *(const int4*)&Alds[arow + mi * 16 * 128 + pc0];
            t.h2[1] = *(const int4*)&Alds[arow + mi * 16 * 128 + pc1];
            af[mi] = t.v;
        }
#pragma unroll
        for (int ni = 0; ni < 8; ni++) {
            AB t;
            t.h2[0] = *(const int4*)&Blds[brow[ni] + pc0];
            t.h2[1] = *(const int4*)&Blds[brow[ni] + pc1];
            bfr[ni] = t.v;
        }
#pragma unroll
        for (int mi = 0; mi < 2; mi++)
#pragma unroll
            for (int ni = 0; ni < 8; ni++)
                acc[mi][ni] = MFMA_MX(af[mi], bfr[ni], acc[mi][ni]);
    }

    // fused epilogue: mu = acc[mi][ci]/256 + b2[c]; ls = acc[mi][ci+4]/256
    //  + b2[D+c] (clamped); x[row][perm[c]] = z[row][perm[c]]*exp(ls)+mu.
    // Math identical to the old f32 finale path.
    const float inv = 1.0f / 256.0f;
    float bmu[4], bls[4];
    int   pcv[4];
#pragma unroll
    for (int ci = 0; ci < 4; ci++) {
        const int gc = n0 + wn + ci * 16 + l16;
        bmu[ci] = b2[gc];
        bls[ci] = b2[D + gc];
        pcv[ci] = perm[gc];
    }
#pragma unroll
    for (int mi = 0; mi < 2; mi++) {
        const int row0 = m0 + wm + mi * 16 + quad * 4;
#pragma unroll
        for (int ci = 0; ci < 4; ci++) {
#pragma unroll
            for (int r = 0; r < 4; r++) {
                const size_t idx = (size_t)(row0 + r) * D + pcv[ci];
                const float mu = acc[mi][ci][r] * inv + bmu[ci];
                float ls = acc[mi][ci + 4][r] * inv + bls[ci];
                ls = fminf(fmaxf(ls, -30.0f), 30.0f);
                out[idx] = z[idx] * expf(ls) + mu;
            }
        }
    }

    // log_det: out[B*D + b] = ld[b] + sum(b2[D:2D))   (nb==0 blocks only)
    if (nb == 0) {
        float bs = 0.0f;
        for (int i = tid; i < D; i += 256) bs += b2[D + i];
#pragma unroll
        for (int o = 32; o > 0; o >>= 1) bs += __shfl_down(bs, o, 64);
        if ((tid & 63) == 0) red[tid >> 6] = bs;
        __syncthreads();
        if (tid < 64)
            out[(size_t)B * D + m0 + tid] =
                ld[m0 + tid] + red[0] + red[1] + red[2] + red[3];
    }
}

// ---------------------------------------------------------------------------
extern "C" void kernel_launch(void* const* d_in, const int* in_sizes, int n_in,
                              void* d_out, int out_size, void* d_ws, size_t ws_size,
                              hipStream_t stream) {
    const float* z    = (const float*)d_in[0];
    const float* W1   = (const float*)d_in[1];
    const float* b1   = (const float*)d_in[2];
    const float* W2   = (const float*)d_in[3];
    const float* b2   = (const float*)d_in[4];
    const int*   perm = (const int*)d_in[5];
    float* out = (float*)d_out;
    char*  ws  = (char*)d_ws;

    const int D = in_sizes[5];          // 1024
    const int H = in_sizes[2];          // 4096
    const int B = in_sizes[0] / D;      // 4096

    const size_t off_h    = 0;                                  // B*H fp8 16MB
    const size_t off_W2mT = off_h    + (size_t)B * H;           // 2D*H fp8 8MB
    const size_t off_W1mT = off_W2mT + (size_t)2 * D * H;       // H*D i8  4MB
    const size_t off_zp   = off_W1mT + (size_t)H * D;           // B*D i8  4MB
    const size_t off_ws2  = off_zp   + (size_t)B * D;           // H*4
    const size_t off_ld   = off_ws2  + (size_t)H * 4;           // B*4

    uint8_t* h    = (uint8_t*)(ws + off_h);
    uint8_t* W2mT = (uint8_t*)(ws + off_W2mT);
    int8_t*  W1mT = (int8_t*)(ws + off_W1mT);
    int8_t*  zp   = (int8_t*)(ws + off_zp);
    float*   ws2  = (float*)(ws + off_ws2);
    float*   ld   = (float*)(ws + off_ld);

    // mt1 also zeroes ld (B) + ws2 (H) in its first blocks
    mt1_k<<<dim3(H / 64, D / 64), 256, 0, stream>>>(W1, W1mT, D, H, D, ld, ws2, B);
    mt2_k<<<dim3(2 * D / 64, H / 64), 256, 0, stream>>>(W2, W2mT, ws2, H, 2 * D, D);
    perm_k<<<dim3(D / 256, B), 256, 0, stream>>>(z, perm, zp, D);

    // h = fp8(relu((zp @ W1m)/32768 + b1)) + fused ld partials [M=B,N=H,K=D]
    gemm1_k<<<(H / 128) * (B / 128), 256, 0, stream>>>(
        zp, W1mT, b1, ws2, h, ld, B, H, D);

    // fused: x = z*exp(log_s)+mu scattered by perm; log_det from ld.
    //   [M=B rows x (D mu-cols + D ls-cols), K=H]
    gemm2f_k<<<(D / 128) * (B / 64), 256, 0, stream>>>(
        h, W2mT, b2, perm, z, ld, out, B, D, H);
}

// Round 2
// 194.444 us; speedup vs baseline: 1.1257x; 1.0668x over previous
//
#include <hip/hip_runtime.h>
#include <stdint.h>

// ---------------------------------------------------------------------------
// MADE flow layer, f32 I/O.
//   h  = relu(zp @ (W1*M1) + b1)     GEMM1: M=4096 N=4096 K=1024 (int8)
//   res= h @ (W2*M2) + b2            GEMM2: M=4096 N=2048 K=4096 (MX-fp8)
//   x[:, perm[i]] = zp*exp(log_s)+mu ; log_det exact via fused h.wsum2
//
// R17 change (vs R16 PASS @207.4us): launch-count reduction probe.
// Accounting showed ~85us of wall time unexplained by kernel durations
// (visible kernels sum to ~120us), and the R15->R16 delta equaled the sum
// of kernel-time changes -> the residual behaves like fixed per-launch
// overhead (~15us x 5-6 dispatches). This round fuses mt1+mt2+perm into
// one block-role-partitioned prep_k (5 -> 3 launches). The mt1-zeroes-ws2 /
// mt2-atomicAdds-ws2 ordering hazard is removed by switching ws2 to
// race-free partials ws2p[16][H] (each second-half mt2 block owns its slot,
// plain stores, no init); gemm1's epilogue sums the 16 partials. perm role
// rebuilt: 2048 blocks (was 16384), int4 perm loads, packed 4B stores.
// GEMM inner loops untouched (gemm2f byte-identical to R16).
// ---------------------------------------------------------------------------

typedef float   f32x4  __attribute__((ext_vector_type(4)));
typedef int     i32x4  __attribute__((ext_vector_type(4)));
typedef int     i32x8  __attribute__((ext_vector_type(8)));

__device__ __forceinline__ uint8_t f2fp8(float f) {
    int p = __builtin_amdgcn_cvt_pk_fp8_f32(f, 0.0f, 0, false);
    return (uint8_t)(p & 0xff);
}
__device__ __forceinline__ int8_t f2i8(float v, float s) {
    float q = rintf(v * s);
    q = fminf(fmaxf(q, -127.0f), 127.0f);
    return (int8_t)q;
}

#define GLD16(g, l)                                                          \
    __builtin_amdgcn_global_load_lds(                                        \
        (const __attribute__((address_space(1))) uint32_t*)(g),              \
        (__attribute__((address_space(3))) uint32_t*)(l), 16, 0, 0)

#define MFMA_MX(a, b, c)                                                     \
    __builtin_amdgcn_mfma_scale_f32_16x16x128_f8f6f4(                        \
        (a), (b), (c), 0, 0, 0, 0x7F7F7F7F, 0, 0x7F7F7F7F)

// ---------------------------------------------------------------------------
// prep_k: fused preprocessing, block-role partitioned (roles are
// data-independent; no cross-role ordering required).
//   role A [0, NB1):        mt1 — W1 (D x H) -> W1mT (H x D) int8 x1024,
//                           masked; first blocks also zero ld[0..B).
//   role B [NB1, NB1+NB2):  mt2 — W2 (H x 2D) -> W2mT (2D x H) fp8 x256,
//                           masked; second-half blocks write ws2 PARTIALS
//                           ws2p[cb][r] (race-free, no init needed).
//   role C [rest, B/2):     perm — zp[b][i] = i8(32 * z[b][perm[i]]),
//                           2 rows/block, packed 4B stores.
// ---------------------------------------------------------------------------
__global__ __launch_bounds__(256) void prep_k(
    const float* __restrict__ W1, int8_t* __restrict__ W1mT,
    const float* __restrict__ W2, uint8_t* __restrict__ W2mT,
    float* __restrict__ ws2p,
    const float* __restrict__ z, const int* __restrict__ perm,
    int8_t* __restrict__ zp, float* __restrict__ ld,
    int D, int H, int B) {
    const int bx  = blockIdx.x;
    const int tid = threadIdx.x;
    const int NB1 = (H / 64) * (D / 64);          // 1024
    const int NB2 = (2 * D / 64) * (H / 64);      // 2048

    if (bx < NB1) {
        // ---- mt1: masked transpose W1 -> int8 ----
        __shared__ int8_t t[64][68];
        const int c0 = (bx % (H / 64)) * 64;      // col in [0,H)
        const int r0 = (bx / (H / 64)) * 64;      // row in [0,D)
        const int tx = tid & 63, ty = tid >> 6;

        const int fid = bx * 256 + tid;
        if (fid < B) ld[fid] = 0.0f;

        for (int rr = ty; rr < 64; rr += 4) {
            const int r = r0 + rr, c = c0 + tx;
            float v = W1[(size_t)r * H + c];
            t[rr][tx] = ((c % (D - 1)) >= r) ? f2i8(v, 1024.0f) : (int8_t)0;
        }
        __syncthreads();
#pragma unroll
        for (int pass = 0; pass < 2; pass++) {
            const int cc = pass * 32 + (tid >> 3);
            const int j0 = (tid & 7) * 8;
            union { int8_t b[8]; uint64_t q; } v;
#pragma unroll
            for (int j = 0; j < 8; j++) v.b[j] = t[j0 + j][cc];
            *(uint64_t*)&W1mT[(size_t)(c0 + cc) * D + r0 + j0] = v.q;
        }
    } else if (bx < NB1 + NB2) {
        // ---- mt2: masked transpose W2 -> fp8 + ws2 partial row-sums ----
        __shared__ uint8_t t[64][68];
        const int idx = bx - NB1;
        const int c0 = (idx % (2 * D / 64)) * 64; // col in [0,2D)
        const int r0 = (idx / (2 * D / 64)) * 64; // row in [0,H)
        const int tx = tid & 63, ty = tid >> 6;
        const bool second = (c0 >= D);
        const int cb = (c0 - D) >> 6;             // partial slot [0,16)

        for (int rr = ty; rr < 64; rr += 4) {
            const int r = r0 + rr, c = c0 + tx;
            float v = W2[(size_t)r * 2 * D + c];
            bool keep = ((c % D) > (r % (D - 1)));
            t[rr][tx] = keep ? f2fp8(v * 256.0f) : (uint8_t)0;
            if (second) {
                float s = keep ? v : 0.0f;
#pragma unroll
                for (int o = 32; o > 0; o >>= 1) s += __shfl_down(s, o, 64);
                if (tx == 0) ws2p[(size_t)cb * H + r] = s;
            }
        }
        __syncthreads();
#pragma unroll
        for (int pass = 0; pass < 2; pass++) {
            const int cc = pass * 32 + (tid >> 3);
            const int j0 = (tid & 7) * 8;
            union { uint8_t b[8]; uint64_t q; } v;
#pragma unroll
            for (int j = 0; j < 8; j++) v.b[j] = t[j0 + j][cc];
            *(uint64_t*)&W2mT[(size_t)(c0 + cc) * H + r0 + j0] = v.q;
        }
    } else {
        // ---- perm+quant: 2 rows/block, 4 elems/thread/row ----
        const int bp = bx - NB1 - NB2;
        const int i0 = tid * 4;                   // D = 1024 = 256*4
        const int4 p4 = *(const int4*)(perm + i0);
#pragma unroll
        for (int rr = 0; rr < 2; rr++) {
            const int b = bp * 2 + rr;
            const float* zr = z + (size_t)b * D;
            union { int8_t b4[4]; uint32_t u; } q;
            q.b4[0] = f2i8(zr[p4.x], 32.0f);
            q.b4[1] = f2i8(zr[p4.y], 32.0f);
            q.b4[2] = f2i8(zr[p4.z], 32.0f);
            q.b4[3] = f2i8(zr[p4.w], 32.0f);
            *(uint32_t*)&zp[(size_t)b * D + i0] = q.u;
        }
    }
}

// ---------------------------------------------------------------------------
// GEMM1 (int8, K=64/MFMA, BK=128, 32KB LDS):
//   h = fp8(relu(acc/32768 + b1)) + fused exact partial log-det (f32 h).
// Inner loop unchanged (validated). Epilogue change: wsum2 read sums the
// 16 race-free partials ws2p[cb][col].
// ---------------------------------------------------------------------------
__global__ __launch_bounds__(256) void gemm1_k(
    const int8_t* __restrict__ A, const int8_t* __restrict__ Bt,
    const float* __restrict__ bias, const float* __restrict__ ws2p,
    uint8_t* __restrict__ Cout, float* __restrict__ ld,
    int M, int N, int K) {
    __shared__ __align__(16) int8_t Alds[128 * 128];
    __shared__ __align__(16) int8_t Blds[128 * 128];
    __shared__ float pdl[128];

    const int id   = blockIdx.x;
    const int xcd  = id & 7, s = id >> 3;     // s in [0,128)
    const int mb   = s & 31;
    const int nb   = xcd * 4 + (s >> 5);
    const int m0   = mb * 128;
    const int n0   = nb * 128;

    const int tid  = threadIdx.x;
    const int lane = tid & 63;
    const int w    = tid >> 6;
    const int wm   = (w & 1) * 64;
    const int wn   = (w >> 1) * 64;
    const int quad = lane >> 4;
    const int l16  = lane & 15;

    i32x4 acc[4][4];
#pragma unroll
    for (int i = 0; i < 4; i++)
#pragma unroll
        for (int j = 0; j < 4; j++) acc[i][j] = (i32x4)0;

    const int8_t* Ag[4];
    const int8_t* Bg[4];
    int8_t *Al[4], *Bl[4];
#pragma unroll
    for (int k = 0; k < 4; k++) {
        const int c  = tid + k * 256;
        const int so = ((c & 7) ^ ((c >> 3) & 7)) * 16;  // bytes
        Ag[k] = A + (size_t)(m0 + (c >> 3)) * K + so;
        Bg[k] = Bt + (size_t)(n0 + (c >> 3)) * K + so;
        Al[k] = &Alds[c * 16];
        Bl[k] = &Blds[c * 16];
    }

    const int sw   = l16 & 7;
    const int arow = (wm + l16) * 128;
    const int brow = (wn + l16) * 128;

    for (int kt = 0; kt < K; kt += 128) {
        __syncthreads();
#pragma unroll
        for (int k = 0; k < 4; k++) {
            GLD16(Ag[k] + kt, Al[k]);
            GLD16(Bg[k] + kt, Bl[k]);
        }
        __syncthreads();

#pragma unroll
        for (int kh = 0; kh < 2; kh++) {
            const int pc = ((kh * 4 + quad) ^ sw) * 16;
            i32x4 af[4], bfr[4];
#pragma unroll
            for (int mi = 0; mi < 4; mi++)
                af[mi] = *(const i32x4*)&Alds[arow + mi * 16 * 128 + pc];
#pragma unroll
            for (int ni = 0; ni < 4; ni++)
                bfr[ni] = *(const i32x4*)&Blds[brow + ni * 16 * 128 + pc];
#pragma unroll
            for (int mi = 0; mi < 4; mi++)
#pragma unroll
                for (int ni = 0; ni < 4; ni++)
                    acc[mi][ni] = __builtin_amdgcn_mfma_i32_16x16x64_i8(
                        af[mi], bfr[ni], acc[mi][ni], 0, 0, 0);
        }
    }

    // epilogue: C/D layout col = lane&15, row = quad*4 + reg;  h = acc/32768+b
    const float inv = 1.0f / 32768.0f;
    float bv[4], wv[4];
#pragma unroll
    for (int ni = 0; ni < 4; ni++) {
        const int col = n0 + wn + ni * 16 + l16;
        bv[ni] = bias[col];
        float sv = 0.0f;
#pragma unroll
        for (int cb = 0; cb < 16; cb++) sv += ws2p[(size_t)cb * N + col];
        wv[ni] = sv;
    }
    float pd[4][4];
#pragma unroll
    for (int mi = 0; mi < 4; mi++)
#pragma unroll
        for (int r = 0; r < 4; r++) pd[mi][r] = 0.0f;

#pragma unroll
    for (int mi = 0; mi < 4; mi++) {
        const int row = m0 + wm + mi * 16 + quad * 4;
#pragma unroll
        for (int ni = 0; ni < 4; ni++) {
            const int col = n0 + wn + ni * 16 + l16;
#pragma unroll
            for (int r = 0; r < 4; r++) {
                float v = fmaxf((float)acc[mi][ni][r] * inv + bv[ni], 0.0f);
                pd[mi][r] += v * wv[ni];
                Cout[(size_t)(row + r) * N + col] = f2fp8(v);
            }
        }
    }

#pragma unroll
    for (int off = 1; off < 16; off <<= 1)
#pragma unroll
        for (int mi = 0; mi < 4; mi++)
#pragma unroll
            for (int r = 0; r < 4; r++)
                pd[mi][r] += __shfl_xor(pd[mi][r], off, 16);

    __syncthreads();
    if ((w >> 1) == 0 && l16 == 0)
#pragma unroll
        for (int mi = 0; mi < 4; mi++)
#pragma unroll
            for (int r = 0; r < 4; r++)
                pdl[wm + mi * 16 + quad * 4 + r] = pd[mi][r];
    __syncthreads();
    if ((w >> 1) == 1 && l16 == 0)
#pragma unroll
        for (int mi = 0; mi < 4; mi++)
#pragma unroll
            for (int r = 0; r < 4; r++)
                pdl[wm + mi * 16 + quad * 4 + r] += pd[mi][r];
    __syncthreads();
    if (tid < 128) atomicAdd(&ld[m0 + tid], pdl[tid]);
}

// ---------------------------------------------------------------------------
// GEMM2 fused (MX fp8, K=128/MFMA, BK=128, 40KB LDS):
//   block = 64 rows x 256 cols, cols = PAIR {[n0,n0+128), [D+n0,D+n0+128)}
//   so each thread holds matching mu (acc ni<4) and log_s (acc ni>=4) for
//   the same column -> epilogue computes x = z*exp(ls)+mu directly.
//   nb==0 blocks also write log_det = ld[b] + sum(b2[D:]).
//   (unchanged from R16 — validated)
// ---------------------------------------------------------------------------
__global__ __launch_bounds__(256) void gemm2f_k(
    const uint8_t* __restrict__ A, const uint8_t* __restrict__ Bt,
    const float* __restrict__ b2, const int* __restrict__ perm,
    const float* __restrict__ z, const float* __restrict__ ld,
    float* __restrict__ out, int B, int D, int K) {
    __shared__ __align__(16) uint8_t Alds[64 * 128];
    __shared__ __align__(16) uint8_t Blds[256 * 128];
    __shared__ float red[4];

    const int id   = blockIdx.x;
    const int nb   = id & 7;          // n-pair block (8 total)
    const int s    = id >> 3;         // m-block (64 total)
    const int m0   = s * 64;
    const int n0   = nb * 128;

    const int tid  = threadIdx.x;
    const int lane = tid & 63;
    const int w    = tid >> 6;
    const int wm   = (w & 1) * 32;
    const int wn   = (w >> 1) * 64;
    const int quad = lane >> 4;
    const int l16  = lane & 15;

    f32x4 acc[2][8];
#pragma unroll
    for (int i = 0; i < 2; i++)
#pragma unroll
        for (int j = 0; j < 8; j++) acc[i][j] = (f32x4)0.0f;

    // staging: A = 64 rows x 128B (2 chunks/thread), B = 256 rows x 128B
    // (8 chunks/thread); rows 0..127 of B-tile = mu cols, 128..255 = ls cols
    const uint8_t* Ag[2];
    uint8_t* Al[2];
#pragma unroll
    for (int k = 0; k < 2; k++) {
        const int c  = tid + k * 256;
        const int so = ((c & 7) ^ ((c >> 3) & 7)) * 16;  // bytes
        Ag[k] = A + (size_t)(m0 + (c >> 3)) * K + so;
        Al[k] = &Alds[c * 16];
    }
    const uint8_t* Bg[8];
    uint8_t* Bl[8];
#pragma unroll
    for (int k = 0; k < 8; k++) {
        const int c  = tid + k * 256;
        const int r  = c >> 3;
        const int g  = (r < 128) ? (n0 + r) : (D + n0 + (r - 128));
        const int so = ((c & 7) ^ (r & 7)) * 16;  // bytes
        Bg[k] = Bt + (size_t)g * K + so;
        Bl[k] = &Blds[c * 16];
    }

    const int sw   = l16 & 7;
    const int pc0  = ((quad * 2) ^ sw) * 16;
    const int pc1  = ((quad * 2 + 1) ^ sw) * 16;
    const int arow = (wm + l16) * 128;
    int brow[8];
#pragma unroll
    for (int ni = 0; ni < 8; ni++)
        brow[ni] = ((ni >> 2) * 128 + wn + (ni & 3) * 16 + l16) * 128;

    for (int kt = 0; kt < K; kt += 128) {
        __syncthreads();
#pragma unroll
        for (int k = 0; k < 2; k++) GLD16(Ag[k] + kt, Al[k]);
#pragma unroll
        for (int k = 0; k < 8; k++) GLD16(Bg[k] + kt, Bl[k]);
        __syncthreads();

        union AB { int4 h2[2]; i32x8 v; };
        i32x8 af[2], bfr[8];
#pragma unroll
        for (int mi = 0; mi < 2; mi++) {
            AB t;
            t.h2[0] = *(const int4*)&Alds[arow + mi * 16 * 128 + pc0];
            t.h2[1] = *(const int4*)&Alds[arow + mi * 16 * 128 + pc1];
            af[mi] = t.v;
        }
#pragma unroll
        for (int ni = 0; ni < 8; ni++) {
            AB t;
            t.h2[0] = *(const int4*)&Blds[brow[ni] + pc0];
            t.h2[1] = *(const int4*)&Blds[brow[ni] + pc1];
            bfr[ni] = t.v;
        }
#pragma unroll
        for (int mi = 0; mi < 2; mi++)
#pragma unroll
            for (int ni = 0; ni < 8; ni++)
                acc[mi][ni] = MFMA_MX(af[mi], bfr[ni], acc[mi][ni]);
    }

    // fused epilogue: mu = acc[mi][ci]/256 + b2[c]; ls = acc[mi][ci+4]/256
    //  + b2[D+c] (clamped); x[row][perm[c]] = z[row][perm[c]]*exp(ls)+mu.
    const float inv = 1.0f / 256.0f;
    float bmu[4], bls[4];
    int   pcv[4];
#pragma unroll
    for (int ci = 0; ci < 4; ci++) {
        const int gc = n0 + wn + ci * 16 + l16;
        bmu[ci] = b2[gc];
        bls[ci] = b2[D + gc];
        pcv[ci] = perm[gc];
    }
#pragma unroll
    for (int mi = 0; mi < 2; mi++) {
        const int row0 = m0 + wm + mi * 16 + quad * 4;
#pragma unroll
        for (int ci = 0; ci < 4; ci++) {
#pragma unroll
            for (int r = 0; r < 4; r++) {
                const size_t idx = (size_t)(row0 + r) * D + pcv[ci];
                const float mu = acc[mi][ci][r] * inv + bmu[ci];
                float ls = acc[mi][ci + 4][r] * inv + bls[ci];
                ls = fminf(fmaxf(ls, -30.0f), 30.0f);
                out[idx] = z[idx] * expf(ls) + mu;
            }
        }
    }

    // log_det: out[B*D + b] = ld[b] + sum(b2[D:2D))   (nb==0 blocks only)
    if (nb == 0) {
        float bs = 0.0f;
        for (int i = tid; i < D; i += 256) bs += b2[D + i];
#pragma unroll
        for (int o = 32; o > 0; o >>= 1) bs += __shfl_down(bs, o, 64);
        if ((tid & 63) == 0) red[tid >> 6] = bs;
        __syncthreads();
        if (tid < 64)
            out[(size_t)B * D + m0 + tid] =
                ld[m0 + tid] + red[0] + red[1] + red[2] + red[3];
    }
}

// ---------------------------------------------------------------------------
extern "C" void kernel_launch(void* const* d_in, const int* in_sizes, int n_in,
                              void* d_out, int out_size, void* d_ws, size_t ws_size,
                              hipStream_t stream) {
    const float* z    = (const float*)d_in[0];
    const float* W1   = (const float*)d_in[1];
    const float* b1   = (const float*)d_in[2];
    const float* W2   = (const float*)d_in[3];
    const float* b2   = (const float*)d_in[4];
    const int*   perm = (const int*)d_in[5];
    float* out = (float*)d_out;
    char*  ws  = (char*)d_ws;

    const int D = in_sizes[5];          // 1024
    const int H = in_sizes[2];          // 4096
    const int B = in_sizes[0] / D;      // 4096

    const size_t off_h    = 0;                                  // B*H fp8 16MB
    const size_t off_W2mT = off_h    + (size_t)B * H;           // 2D*H fp8 8MB
    const size_t off_W1mT = off_W2mT + (size_t)2 * D * H;       // H*D i8  4MB
    const size_t off_zp   = off_W1mT + (size_t)H * D;           // B*D i8  4MB
    const size_t off_ws2  = off_zp   + (size_t)B * D;           // 16*H*4 256KB
    const size_t off_ld   = off_ws2  + (size_t)16 * H * 4;      // B*4

    uint8_t* h    = (uint8_t*)(ws + off_h);
    uint8_t* W2mT = (uint8_t*)(ws + off_W2mT);
    int8_t*  W1mT = (int8_t*)(ws + off_W1mT);
    int8_t*  zp   = (int8_t*)(ws + off_zp);
    float*   ws2p = (float*)(ws + off_ws2);
    float*   ld   = (float*)(ws + off_ld);

    // fused preprocessing: mt1 (+ ld zero) | mt2 (+ ws2 partials) | perm
    const int NB1 = (H / 64) * (D / 64);       // 1024
    const int NB2 = (2 * D / 64) * (H / 64);   // 2048
    const int NBP = B / 2;                     // 2048
    prep_k<<<NB1 + NB2 + NBP, 256, 0, stream>>>(
        W1, W1mT, W2, W2mT, ws2p, z, perm, zp, ld, D, H, B);

    // h = fp8(relu((zp @ W1m)/32768 + b1)) + fused ld partials [M=B,N=H,K=D]
    gemm1_k<<<(H / 128) * (B / 128), 256, 0, stream>>>(
        zp, W1mT, b1, ws2p, h, ld, B, H, D);

    // fused: x = z*exp(log_s)+mu scattered by perm; log_det from ld.
    //   [M=B rows x (D mu-cols + D ls-cols), K=H]
    gemm2f_k<<<(D / 128) * (B / 64), 256, 0, stream>>>(
        h, W2mT, b2, perm, z, ld, out, B, D, H);
}

// Round 3
// 189.179 us; speedup vs baseline: 1.1570x; 1.0278x over previous
//
#include <hip/hip_runtime.h>
#include <stdint.h>

// ---------------------------------------------------------------------------
// MADE flow layer, f32 I/O.
//   h  = relu(zp @ (W1*M1) + b1)     GEMM1: M=4096 N=4096 K=1024 (int8)
//   res= h @ (W2*M2) + b2            GEMM2: M=4096 N=2048 K=4096 (MX-fp8)
//   x[:, perm[i]] = zp*exp(log_s)+mu ; log_det exact via fused h.wsum2
//
// R18 change (vs R17 PASS @194.4us): gemm2f reshape + 2-phase prefetch.
// R17 counters: gemm2f 51us, MfmaUtil 25%, occupancy 18%. The 64x256 tile
// staged 40KB/step for 64 block-MFMAs (ds_read:MFMA = 20:16/wave) with the
// two-barrier m97 structure (vmcnt(0) drain, no overlap, ~1.5 blocks/CU).
// New gemm2f: 128 rows x 64 col-pairs (same 512-block grid, pairing kept:
// B-tile rows 0-63 = mu cols, 64-127 = ls cols), A 16KB + B 16KB per step
// (-20% staging, 16:16 read:MFMA), double-buffered 64KB LDS (2 blocks/CU),
// T3-minimum prefetch: issue next-tile global_load_lds BEFORE ds_read+MFMA,
// ONE __syncthreads per K-step (was 2). Arithmetic bit-identical to R17.
// prep_k / gemm1_k untouched (validated).
// ---------------------------------------------------------------------------

typedef float   f32x4  __attribute__((ext_vector_type(4)));
typedef int     i32x4  __attribute__((ext_vector_type(4)));
typedef int     i32x8  __attribute__((ext_vector_type(8)));

__device__ __forceinline__ uint8_t f2fp8(float f) {
    int p = __builtin_amdgcn_cvt_pk_fp8_f32(f, 0.0f, 0, false);
    return (uint8_t)(p & 0xff);
}
__device__ __forceinline__ int8_t f2i8(float v, float s) {
    float q = rintf(v * s);
    q = fminf(fmaxf(q, -127.0f), 127.0f);
    return (int8_t)q;
}

#define GLD16(g, l)                                                          \
    __builtin_amdgcn_global_load_lds(                                        \
        (const __attribute__((address_space(1))) uint32_t*)(g),              \
        (__attribute__((address_space(3))) uint32_t*)(l), 16, 0, 0)

#define MFMA_MX(a, b, c)                                                     \
    __builtin_amdgcn_mfma_scale_f32_16x16x128_f8f6f4(                        \
        (a), (b), (c), 0, 0, 0, 0x7F7F7F7F, 0, 0x7F7F7F7F)

// ---------------------------------------------------------------------------
// prep_k: fused preprocessing, block-role partitioned (unchanged from R17).
// ---------------------------------------------------------------------------
__global__ __launch_bounds__(256) void prep_k(
    const float* __restrict__ W1, int8_t* __restrict__ W1mT,
    const float* __restrict__ W2, uint8_t* __restrict__ W2mT,
    float* __restrict__ ws2p,
    const float* __restrict__ z, const int* __restrict__ perm,
    int8_t* __restrict__ zp, float* __restrict__ ld,
    int D, int H, int B) {
    const int bx  = blockIdx.x;
    const int tid = threadIdx.x;
    const int NB1 = (H / 64) * (D / 64);          // 1024
    const int NB2 = (2 * D / 64) * (H / 64);      // 2048

    if (bx < NB1) {
        // ---- mt1: masked transpose W1 -> int8 ----
        __shared__ int8_t t[64][68];
        const int c0 = (bx % (H / 64)) * 64;      // col in [0,H)
        const int r0 = (bx / (H / 64)) * 64;      // row in [0,D)
        const int tx = tid & 63, ty = tid >> 6;

        const int fid = bx * 256 + tid;
        if (fid < B) ld[fid] = 0.0f;

        for (int rr = ty; rr < 64; rr += 4) {
            const int r = r0 + rr, c = c0 + tx;
            float v = W1[(size_t)r * H + c];
            t[rr][tx] = ((c % (D - 1)) >= r) ? f2i8(v, 1024.0f) : (int8_t)0;
        }
        __syncthreads();
#pragma unroll
        for (int pass = 0; pass < 2; pass++) {
            const int cc = pass * 32 + (tid >> 3);
            const int j0 = (tid & 7) * 8;
            union { int8_t b[8]; uint64_t q; } v;
#pragma unroll
            for (int j = 0; j < 8; j++) v.b[j] = t[j0 + j][cc];
            *(uint64_t*)&W1mT[(size_t)(c0 + cc) * D + r0 + j0] = v.q;
        }
    } else if (bx < NB1 + NB2) {
        // ---- mt2: masked transpose W2 -> fp8 + ws2 partial row-sums ----
        __shared__ uint8_t t[64][68];
        const int idx = bx - NB1;
        const int c0 = (idx % (2 * D / 64)) * 64; // col in [0,2D)
        const int r0 = (idx / (2 * D / 64)) * 64; // row in [0,H)
        const int tx = tid & 63, ty = tid >> 6;
        const bool second = (c0 >= D);
        const int cb = (c0 - D) >> 6;             // partial slot [0,16)

        for (int rr = ty; rr < 64; rr += 4) {
            const int r = r0 + rr, c = c0 + tx;
            float v = W2[(size_t)r * 2 * D + c];
            bool keep = ((c % D) > (r % (D - 1)));
            t[rr][tx] = keep ? f2fp8(v * 256.0f) : (uint8_t)0;
            if (second) {
                float s = keep ? v : 0.0f;
#pragma unroll
                for (int o = 32; o > 0; o >>= 1) s += __shfl_down(s, o, 64);
                if (tx == 0) ws2p[(size_t)cb * H + r] = s;
            }
        }
        __syncthreads();
#pragma unroll
        for (int pass = 0; pass < 2; pass++) {
            const int cc = pass * 32 + (tid >> 3);
            const int j0 = (tid & 7) * 8;
            union { uint8_t b[8]; uint64_t q; } v;
#pragma unroll
            for (int j = 0; j < 8; j++) v.b[j] = t[j0 + j][cc];
            *(uint64_t*)&W2mT[(size_t)(c0 + cc) * H + r0 + j0] = v.q;
        }
    } else {
        // ---- perm+quant: 2 rows/block, 4 elems/thread/row ----
        const int bp = bx - NB1 - NB2;
        const int i0 = tid * 4;                   // D = 1024 = 256*4
        const int4 p4 = *(const int4*)(perm + i0);
#pragma unroll
        for (int rr = 0; rr < 2; rr++) {
            const int b = bp * 2 + rr;
            const float* zr = z + (size_t)b * D;
            union { int8_t b4[4]; uint32_t u; } q;
            q.b4[0] = f2i8(zr[p4.x], 32.0f);
            q.b4[1] = f2i8(zr[p4.y], 32.0f);
            q.b4[2] = f2i8(zr[p4.z], 32.0f);
            q.b4[3] = f2i8(zr[p4.w], 32.0f);
            *(uint32_t*)&zp[(size_t)b * D + i0] = q.u;
        }
    }
}

// ---------------------------------------------------------------------------
// GEMM1 (int8, K=64/MFMA, BK=128, 32KB LDS):
//   h = fp8(relu(acc/32768 + b1)) + fused exact partial log-det (f32 h).
// (unchanged from R17 — validated)
// ---------------------------------------------------------------------------
__global__ __launch_bounds__(256) void gemm1_k(
    const int8_t* __restrict__ A, const int8_t* __restrict__ Bt,
    const float* __restrict__ bias, const float* __restrict__ ws2p,
    uint8_t* __restrict__ Cout, float* __restrict__ ld,
    int M, int N, int K) {
    __shared__ __align__(16) int8_t Alds[128 * 128];
    __shared__ __align__(16) int8_t Blds[128 * 128];
    __shared__ float pdl[128];

    const int id   = blockIdx.x;
    const int xcd  = id & 7, s = id >> 3;     // s in [0,128)
    const int mb   = s & 31;
    const int nb   = xcd * 4 + (s >> 5);
    const int m0   = mb * 128;
    const int n0   = nb * 128;

    const int tid  = threadIdx.x;
    const int lane = tid & 63;
    const int w    = tid >> 6;
    const int wm   = (w & 1) * 64;
    const int wn   = (w >> 1) * 64;
    const int quad = lane >> 4;
    const int l16  = lane & 15;

    i32x4 acc[4][4];
#pragma unroll
    for (int i = 0; i < 4; i++)
#pragma unroll
        for (int j = 0; j < 4; j++) acc[i][j] = (i32x4)0;

    const int8_t* Ag[4];
    const int8_t* Bg[4];
    int8_t *Al[4], *Bl[4];
#pragma unroll
    for (int k = 0; k < 4; k++) {
        const int c  = tid + k * 256;
        const int so = ((c & 7) ^ ((c >> 3) & 7)) * 16;  // bytes
        Ag[k] = A + (size_t)(m0 + (c >> 3)) * K + so;
        Bg[k] = Bt + (size_t)(n0 + (c >> 3)) * K + so;
        Al[k] = &Alds[c * 16];
        Bl[k] = &Blds[c * 16];
    }

    const int sw   = l16 & 7;
    const int arow = (wm + l16) * 128;
    const int brow = (wn + l16) * 128;

    for (int kt = 0; kt < K; kt += 128) {
        __syncthreads();
#pragma unroll
        for (int k = 0; k < 4; k++) {
            GLD16(Ag[k] + kt, Al[k]);
            GLD16(Bg[k] + kt, Bl[k]);
        }
        __syncthreads();

#pragma unroll
        for (int kh = 0; kh < 2; kh++) {
            const int pc = ((kh * 4 + quad) ^ sw) * 16;
            i32x4 af[4], bfr[4];
#pragma unroll
            for (int mi = 0; mi < 4; mi++)
                af[mi] = *(const i32x4*)&Alds[arow + mi * 16 * 128 + pc];
#pragma unroll
            for (int ni = 0; ni < 4; ni++)
                bfr[ni] = *(const i32x4*)&Blds[brow + ni * 16 * 128 + pc];
#pragma unroll
            for (int mi = 0; mi < 4; mi++)
#pragma unroll
                for (int ni = 0; ni < 4; ni++)
                    acc[mi][ni] = __builtin_amdgcn_mfma_i32_16x16x64_i8(
                        af[mi], bfr[ni], acc[mi][ni], 0, 0, 0);
        }
    }

    // epilogue: C/D layout col = lane&15, row = quad*4 + reg;  h = acc/32768+b
    const float inv = 1.0f / 32768.0f;
    float bv[4], wv[4];
#pragma unroll
    for (int ni = 0; ni < 4; ni++) {
        const int col = n0 + wn + ni * 16 + l16;
        bv[ni] = bias[col];
        float sv = 0.0f;
#pragma unroll
        for (int cb = 0; cb < 16; cb++) sv += ws2p[(size_t)cb * N + col];
        wv[ni] = sv;
    }
    float pd[4][4];
#pragma unroll
    for (int mi = 0; mi < 4; mi++)
#pragma unroll
        for (int r = 0; r < 4; r++) pd[mi][r] = 0.0f;

#pragma unroll
    for (int mi = 0; mi < 4; mi++) {
        const int row = m0 + wm + mi * 16 + quad * 4;
#pragma unroll
        for (int ni = 0; ni < 4; ni++) {
            const int col = n0 + wn + ni * 16 + l16;
#pragma unroll
            for (int r = 0; r < 4; r++) {
                float v = fmaxf((float)acc[mi][ni][r] * inv + bv[ni], 0.0f);
                pd[mi][r] += v * wv[ni];
                Cout[(size_t)(row + r) * N + col] = f2fp8(v);
            }
        }
    }

#pragma unroll
    for (int off = 1; off < 16; off <<= 1)
#pragma unroll
        for (int mi = 0; mi < 4; mi++)
#pragma unroll
            for (int r = 0; r < 4; r++)
                pd[mi][r] += __shfl_xor(pd[mi][r], off, 16);

    __syncthreads();
    if ((w >> 1) == 0 && l16 == 0)
#pragma unroll
        for (int mi = 0; mi < 4; mi++)
#pragma unroll
            for (int r = 0; r < 4; r++)
                pdl[wm + mi * 16 + quad * 4 + r] = pd[mi][r];
    __syncthreads();
    if ((w >> 1) == 1 && l16 == 0)
#pragma unroll
        for (int mi = 0; mi < 4; mi++)
#pragma unroll
            for (int r = 0; r < 4; r++)
                pdl[wm + mi * 16 + quad * 4 + r] += pd[mi][r];
    __syncthreads();
    if (tid < 128) atomicAdd(&ld[m0 + tid], pdl[tid]);
}

// ---------------------------------------------------------------------------
// GEMM2 fused (MX fp8, K=128/MFMA, BK=128, 64KB LDS double-buffered):
//   block = 128 rows x 64 col-pairs; B-tile rows 0-63 = mu cols [p0,p0+64),
//   rows 64-127 = ls cols [D+p0,D+p0+64). Each thread holds matching mu
//   (acc ni<2) and log_s (acc ni>=2) for the same column -> epilogue
//   computes x = z*exp(ls)+mu directly. nb==0 blocks also emit log_det.
//   2-phase prefetch: stage next K-tile into buf^1 BEFORE ds_read+MFMA of
//   buf, one __syncthreads per K-step. Swizzle identical to validated MX
//   structure. Grid: (D/64)*(B/128) = 512; nb = id&15 -> 2 W2-slices/XCD
//   (1MB, L2-resident).
// ---------------------------------------------------------------------------
__global__ __launch_bounds__(256) void gemm2f_k(
    const uint8_t* __restrict__ A, const uint8_t* __restrict__ Bt,
    const float* __restrict__ b2, const int* __restrict__ perm,
    const float* __restrict__ z, const float* __restrict__ ld,
    float* __restrict__ out, int B, int D, int K) {
    __shared__ __align__(16) uint8_t Alds[2][128 * 128];
    __shared__ __align__(16) uint8_t Blds[2][128 * 128];
    __shared__ float red[4];

    const int id   = blockIdx.x;
    const int nb   = id & 15;         // col-pair block [0,16)
    const int s    = id >> 4;         // m-block [0,32)
    const int m0   = s * 128;
    const int p0   = nb * 64;         // col-pair base

    const int tid  = threadIdx.x;
    const int lane = tid & 63;
    const int w    = tid >> 6;
    const int wm   = (w & 1) * 64;    // wave rows
    const int wp   = (w >> 1) * 32;   // wave col-pairs
    const int quad = lane >> 4;
    const int l16  = lane & 15;

    f32x4 acc[4][4];
#pragma unroll
    for (int i = 0; i < 4; i++)
#pragma unroll
        for (int j = 0; j < 4; j++) acc[i][j] = (f32x4)0.0f;

    // staging: A = 128 rows x 128B, B = 128 rows x 128B (4 chunks/thread ea)
    const uint8_t* Ag[4];
    const uint8_t* Bg[4];
    int ldso[4];
#pragma unroll
    for (int k = 0; k < 4; k++) {
        const int c  = tid + k * 256;
        const int r  = c >> 3;
        const int so = ((c & 7) ^ (r & 7)) * 16;  // bytes
        Ag[k] = A + (size_t)(m0 + r) * K + so;
        const int g = (r < 64) ? (p0 + r) : (D + p0 + (r - 64));
        Bg[k] = Bt + (size_t)g * K + so;
        ldso[k] = c * 16;
    }

    const int sw   = l16 & 7;
    const int pc0  = ((quad * 2) ^ sw) * 16;
    const int pc1  = ((quad * 2 + 1) ^ sw) * 16;

    // prologue: stage K-tile 0 into buf 0
#pragma unroll
    for (int k = 0; k < 4; k++) {
        GLD16(Ag[k], &Alds[0][ldso[k]]);
        GLD16(Bg[k], &Blds[0][ldso[k]]);
    }
    __syncthreads();

    int cur = 0;
    for (int kt = 0; kt < K; kt += 128) {
        const int nxt = cur ^ 1;
        if (kt + 128 < K) {
#pragma unroll
            for (int k = 0; k < 4; k++) {
                GLD16(Ag[k] + kt + 128, &Alds[nxt][ldso[k]]);
                GLD16(Bg[k] + kt + 128, &Blds[nxt][ldso[k]]);
            }
        }
        union ABu { int4 h2[2]; i32x8 v; };
        i32x8 af[4], bfr[4];
#pragma unroll
        for (int mi = 0; mi < 4; mi++) {
            ABu t;
            const int ar = (wm + mi * 16 + l16) * 128;
            t.h2[0] = *(const int4*)&Alds[cur][ar + pc0];
            t.h2[1] = *(const int4*)&Alds[cur][ar + pc1];
            af[mi] = t.v;
        }
#pragma unroll
        for (int ni = 0; ni < 4; ni++) {
            ABu t;
            const int br = ((ni >> 1) * 64 + wp + (ni & 1) * 16 + l16) * 128;
            t.h2[0] = *(const int4*)&Blds[cur][br + pc0];
            t.h2[1] = *(const int4*)&Blds[cur][br + pc1];
            bfr[ni] = t.v;
        }
#pragma unroll
        for (int mi = 0; mi < 4; mi++)
#pragma unroll
            for (int ni = 0; ni < 4; ni++)
                acc[mi][ni] = MFMA_MX(af[mi], bfr[ni], acc[mi][ni]);
        __syncthreads();   // drains prefetch (vmcnt) + covers LDS reuse
        cur = nxt;
    }

    // fused epilogue: mu = acc[mi][ci]/256 + b2[c]; ls = acc[mi][ci+2]/256
    //  + b2[D+c] (clamped); x[row][perm[c]] = z[row][perm[c]]*exp(ls)+mu.
    const float inv = 1.0f / 256.0f;
    float bmu[2], bls[2];
    int   pcv[2];
#pragma unroll
    for (int ci = 0; ci < 2; ci++) {
        const int gc = p0 + wp + ci * 16 + l16;
        bmu[ci] = b2[gc];
        bls[ci] = b2[D + gc];
        pcv[ci] = perm[gc];
    }
#pragma unroll
    for (int mi = 0; mi < 4; mi++) {
        const int row0 = m0 + wm + mi * 16 + quad * 4;
#pragma unroll
        for (int ci = 0; ci < 2; ci++) {
#pragma unroll
            for (int r = 0; r < 4; r++) {
                const size_t idx = (size_t)(row0 + r) * D + pcv[ci];
                const float mu = acc[mi][ci][r] * inv + bmu[ci];
                float ls = acc[mi][ci + 2][r] * inv + bls[ci];
                ls = fminf(fmaxf(ls, -30.0f), 30.0f);
                out[idx] = z[idx] * expf(ls) + mu;
            }
        }
    }

    // log_det: out[B*D + b] = ld[b] + sum(b2[D:2D))   (nb==0 blocks only)
    if (nb == 0) {
        float bs = 0.0f;
        for (int i = tid; i < D; i += 256) bs += b2[D + i];
#pragma unroll
        for (int o = 32; o > 0; o >>= 1) bs += __shfl_down(bs, o, 64);
        if ((tid & 63) == 0) red[tid >> 6] = bs;
        __syncthreads();
        if (tid < 128)
            out[(size_t)B * D + m0 + tid] =
                ld[m0 + tid] + red[0] + red[1] + red[2] + red[3];
    }
}

// ---------------------------------------------------------------------------
extern "C" void kernel_launch(void* const* d_in, const int* in_sizes, int n_in,
                              void* d_out, int out_size, void* d_ws, size_t ws_size,
                              hipStream_t stream) {
    const float* z    = (const float*)d_in[0];
    const float* W1   = (const float*)d_in[1];
    const float* b1   = (const float*)d_in[2];
    const float* W2   = (const float*)d_in[3];
    const float* b2   = (const float*)d_in[4];
    const int*   perm = (const int*)d_in[5];
    float* out = (float*)d_out;
    char*  ws  = (char*)d_ws;

    const int D = in_sizes[5];          // 1024
    const int H = in_sizes[2];          // 4096
    const int B = in_sizes[0] / D;      // 4096

    const size_t off_h    = 0;                                  // B*H fp8 16MB
    const size_t off_W2mT = off_h    + (size_t)B * H;           // 2D*H fp8 8MB
    const size_t off_W1mT = off_W2mT + (size_t)2 * D * H;       // H*D i8  4MB
    const size_t off_zp   = off_W1mT + (size_t)H * D;           // B*D i8  4MB
    const size_t off_ws2  = off_zp   + (size_t)B * D;           // 16*H*4 256KB
    const size_t off_ld   = off_ws2  + (size_t)16 * H * 4;      // B*4

    uint8_t* h    = (uint8_t*)(ws + off_h);
    uint8_t* W2mT = (uint8_t*)(ws + off_W2mT);
    int8_t*  W1mT = (int8_t*)(ws + off_W1mT);
    int8_t*  zp   = (int8_t*)(ws + off_zp);
    float*   ws2p = (float*)(ws + off_ws2);
    float*   ld   = (float*)(ws + off_ld);

    // fused preprocessing: mt1 (+ ld zero) | mt2 (+ ws2 partials) | perm
    const int NB1 = (H / 64) * (D / 64);       // 1024
    const int NB2 = (2 * D / 64) * (H / 64);   // 2048
    const int NBP = B / 2;                     // 2048
    prep_k<<<NB1 + NB2 + NBP, 256, 0, stream>>>(
        W1, W1mT, W2, W2mT, ws2p, z, perm, zp, ld, D, H, B);

    // h = fp8(relu((zp @ W1m)/32768 + b1)) + fused ld partials [M=B,N=H,K=D]
    gemm1_k<<<(H / 128) * (B / 128), 256, 0, stream>>>(
        zp, W1mT, b1, ws2p, h, ld, B, H, D);

    // fused: x = z*exp(log_s)+mu scattered by perm; log_det from ld.
    //   [M=B rows x D col-pairs, K=H]  grid = (D/64)*(B/128) = 512
    gemm2f_k<<<(D / 64) * (B / 128), 256, 0, stream>>>(
        h, W2mT, b2, perm, z, ld, out, B, D, H);
}